// Round 11
// baseline (163.376 us; speedup 1.0000x reference)
//
#include <hip/hip_runtime.h>
#include <hip/hip_bf16.h>
#include <cstddef>

#define BB 2
#define HH 64
#define WW 64
#define SCALE 0.17677669529663687f   // 32^-0.5

// natten tile geometry: 4x8 queries per block, ONE head
#define HALO_H 10
#define HALO_W 14
#define NPIX 140
#define NQ 32

// measurement amplification factors (kernels are idempotent; reps only
// multiply the work so per-kernel cost = amplified_dur / REP)
#define REP_QKV 16
#define REP_NAT 10
#define REP_PROJ 16

typedef short short8 __attribute__((ext_vector_type(8)));
typedef float f32x4 __attribute__((ext_vector_type(4)));

__device__ inline ushort f2bf(float f) {
    union { __hip_bfloat16 b; ushort u; } cv;
    cv.b = __float2bfloat16(f);
    return cv.u;
}
__device__ inline float bflo(uint u) { union { uint i; float f; } c; c.i = u << 16; return c.f; }
__device__ inline float bfhi(uint u) { union { uint i; float f; } c; c.i = u & 0xffff0000u; return c.f; }

// ---------------------------------------------------------------------------
// K0: weight transpose f32 -> bf16, LDS-tiled (round-7 proven). NOT amplified.
// ---------------------------------------------------------------------------
__global__ __launch_bounds__(256) void cvt_w_kernel(
    const float* __restrict__ w_qkv, const float* __restrict__ w_proj,
    ushort* __restrict__ Wt)
{
    __shared__ float Ws[128 * 65];
    const int tid = threadIdx.x;
    const int blk = blockIdx.x;
    const float* src = (blk < 6) ? w_qkv : w_proj;
    const int srcN  = (blk < 6) ? 384 : 128;
    const int n0    = (blk < 6) ? blk * 64 : (blk - 6) * 64;
    const int obase = (blk < 6) ? n0 : 384 + n0;

    #pragma unroll
    for (int t = 0; t < 8; ++t) {
        int idx = tid + t * 256;
        int k = idx >> 4, c4 = idx & 15;
        float4 v = *(const float4*)(src + (size_t)k * srcN + n0 + c4 * 4);
        Ws[k * 65 + c4 * 4 + 0] = v.x;
        Ws[k * 65 + c4 * 4 + 1] = v.y;
        Ws[k * 65 + c4 * 4 + 2] = v.z;
        Ws[k * 65 + c4 * 4 + 3] = v.w;
    }
    __syncthreads();

    const int n = tid & 63;
    #pragma unroll
    for (int t = 0; t < 4; ++t) {
        int c = (tid >> 6) + t * 4;
        union { ushort s[8]; uint4 q; } u;
        #pragma unroll
        for (int e = 0; e < 8; ++e) u.s[e] = f2bf(Ws[(c * 8 + e) * 65 + n]);
        *(uint4*)&Wt[(size_t)(obase + n) * 128 + c * 8] = u.q;
    }
}

// ---------------------------------------------------------------------------
// K1: qkv GEMM (round-7 proven), amplified x REP_QKV for measurement.
// ---------------------------------------------------------------------------
__global__ __launch_bounds__(256) void qkv_gemm_kernel(
    const float* __restrict__ x, const ushort* __restrict__ Wt,
    const float* __restrict__ b_qkv, ushort* __restrict__ qkv)
{
    __shared__ ushort As[64 * 128];
    __shared__ ushort Bs[192 * 128];

    const int tid = threadIdx.x;
    const int m0 = blockIdx.x * 64;
    const int n0 = blockIdx.y * 192;

    for (int rep = 0; rep < REP_QKV; ++rep) {
    #pragma unroll
    for (int t = 0; t < 4; ++t) {
        int idx = tid + t * 256;
        int r = idx >> 4, c = idx & 15;
        const float* src = x + (size_t)(m0 + r) * 128 + c * 8;
        float4 v0 = *(const float4*)src;
        float4 v1 = *(const float4*)(src + 4);
        union { ushort s[8]; uint4 q; } u;
        u.s[0] = f2bf(v0.x); u.s[1] = f2bf(v0.y); u.s[2] = f2bf(v0.z); u.s[3] = f2bf(v0.w);
        u.s[4] = f2bf(v1.x); u.s[5] = f2bf(v1.y); u.s[6] = f2bf(v1.z); u.s[7] = f2bf(v1.w);
        *(uint4*)&As[r * 128 + (c ^ (r & 7)) * 8] = u.q;
    }
    #pragma unroll
    for (int t = 0; t < 12; ++t) {
        int idx = tid + t * 256;
        int r = idx >> 4, c = idx & 15;
        uint4 v = *(const uint4*)(Wt + (size_t)(n0 + r) * 128 + c * 8);
        *(uint4*)&Bs[r * 128 + (c ^ (r & 7)) * 8] = v;
    }
    __syncthreads();

    const int wid = tid >> 6, lane = tid & 63;
    const int l15 = lane & 15, l4 = lane >> 4;
    const int mr = (wid >> 1) * 32, nr = (wid & 1) * 96;

    f32x4 acc[2][6] = {};
    #pragma unroll
    for (int ks = 0; ks < 4; ++ks) {
        short8 af[2], bf[6];
        #pragma unroll
        for (int fm = 0; fm < 2; ++fm) {
            int row = mr + fm * 16 + l15;
            af[fm] = *(const short8*)&As[row * 128 + ((ks * 4 + l4) ^ (row & 7)) * 8];
        }
        #pragma unroll
        for (int fn = 0; fn < 6; ++fn) {
            int row = nr + fn * 16 + l15;
            bf[fn] = *(const short8*)&Bs[row * 128 + ((ks * 4 + l4) ^ (row & 7)) * 8];
        }
        #pragma unroll
        for (int fm = 0; fm < 2; ++fm)
            #pragma unroll
            for (int fn = 0; fn < 6; ++fn)
                acc[fm][fn] = __builtin_amdgcn_mfma_f32_16x16x32_bf16(
                    af[fm], bf[fn], acc[fm][fn], 0, 0, 0);
    }

    __syncthreads();
    ushort* C_s = Bs;                     // 64 x 200 overlay
    #pragma unroll
    for (int fn = 0; fn < 6; ++fn) {
        int colb = nr + fn * 16;
        int col = colb + l15;
        float bc = b_qkv[n0 + col];
        float sc = (n0 + colb < 128) ? SCALE : 1.0f;
        #pragma unroll
        for (int fm = 0; fm < 2; ++fm)
            #pragma unroll
            for (int reg = 0; reg < 4; ++reg) {
                int row = mr + fm * 16 + l4 * 4 + reg;
                C_s[row * 200 + col] = f2bf((acc[fm][fn][reg] + bc) * sc);
            }
    }
    __syncthreads();
    #pragma unroll
    for (int t = 0; t < 6; ++t) {
        int idx = tid + t * 256;
        int row = idx / 24, c = idx - row * 24;
        uint4 v = *(const uint4*)&C_s[row * 200 + c * 8];
        *(uint4*)&qkv[(size_t)(m0 + row) * 384 + n0 + c * 8] = v;
    }
    __syncthreads();   // rep boundary: C_s reads done before next staging
    }
}

// ---------------------------------------------------------------------------
// K2: neighborhood attention (round-9 proven), amplified x REP_NAT.
// ---------------------------------------------------------------------------
__global__ __launch_bounds__(256) void natten_head_kernel(
    const ushort* __restrict__ qkv,     // (B*H*W) x 384 bf16, q pre-scaled
    const float* __restrict__ rpb,      // 4 x 13 x 13
    ushort* __restrict__ attn_out)      // (B*H*W) x 128 bf16
{
    __shared__ ushort KV_s[NPIX * 64];
    __shared__ float attn_s[NQ * 52];
    __shared__ float rpb_s[169];

    const int hd = blockIdx.y;
    const int tid = threadIdx.x;
    const int bx = ((blockIdx.x & 7) << 5) | (blockIdx.x >> 3);
    const int b  = bx >> 7;
    const int th = (bx >> 3) & 15;
    const int tw = bx & 7;
    const int h0 = th * 4, w0 = tw * 8;
    const int ho = max(0, h0 - 3), wo = max(0, w0 - 3);

    const int q = tid >> 3, t8 = tid & 7;
    const int qh = h0 + (q >> 3), qw = w0 + (q & 7);
    const int hs = min(max(qh - 3, 0), HH - 7);
    const int ws = min(max(qw - 3, 0), WW - 7);
    const int base_lp = (hs - ho) * HALO_W + (ws - wo);
    const int bh0 = hs - qh + 6, bw0 = ws - qw + 6;
    const size_t qpix = (size_t)((b << 12) + (qh << 6) + qw);

    for (int rep = 0; rep < REP_NAT; ++rep) {
    #pragma unroll
    for (int t = 0; t < 5; ++t) {
        int idx = tid + t * 256;
        if (idx < NPIX * 8) {
            int pix = idx >> 3, s = idx & 7;
            int r = pix / HALO_W, c = pix - r * HALO_W;
            int gh = min(ho + r, HH - 1), gw = min(wo + c, WW - 1);
            const ushort* gp = qkv + (size_t)((b << 12) + (gh << 6) + gw) * 384
                               + 128 + (s >> 2) * 128 + hd * 32 + (s & 3) * 8;
            uint4 v = *(const uint4*)gp;
            int bb = (pix >> 2) & 1;
            int slot = (2 * ((s & 3) ^ (pix & 3)) ^ bb) ^ (s >> 2);
            *(uint4*)&KV_s[pix * 64 + slot * 8] = v;
        }
    }
    if (tid < 169) rpb_s[tid] = rpb[hd * 169 + tid];

    float qf[32];
    #pragma unroll
    for (int d4 = 0; d4 < 4; ++d4) {
        uint4 qu = *(const uint4*)(qkv + qpix * 384 + hd * 32 + d4 * 8);
        qf[d4*8+0] = bflo(qu.x); qf[d4*8+1] = bfhi(qu.x);
        qf[d4*8+2] = bflo(qu.y); qf[d4*8+3] = bfhi(qu.y);
        qf[d4*8+4] = bflo(qu.z); qf[d4*8+5] = bfhi(qu.z);
        qf[d4*8+6] = bflo(qu.w); qf[d4*8+7] = bfhi(qu.w);
    }
    __syncthreads();

    float lg[7];
    #pragma unroll
    for (int i = 0; i < 7; ++i) {
        int j = t8 + i * 8;
        float s = -1e30f;
        if (j < 49) {
            int p = (j * 37) >> 8;            // exact j/7 for j<=48
            int qq = j - p * 7;
            int lp = base_lp + p * HALO_W + qq;
            int bb = (lp >> 2) & 1;
            float a = 0.f;
            #pragma unroll
            for (int d4 = 0; d4 < 4; ++d4) {
                uint4 ku = *(const uint4*)&KV_s[lp * 64 + ((2 * (d4 ^ (lp & 3)) ^ bb) * 8)];
                a += bflo(ku.x)*qf[d4*8+0] + bfhi(ku.x)*qf[d4*8+1]
                   + bflo(ku.y)*qf[d4*8+2] + bfhi(ku.y)*qf[d4*8+3]
                   + bflo(ku.z)*qf[d4*8+4] + bfhi(ku.z)*qf[d4*8+5]
                   + bflo(ku.w)*qf[d4*8+6] + bfhi(ku.w)*qf[d4*8+7];
            }
            s = a + rpb_s[(bh0 + p) * 13 + (bw0 + qq)];
        }
        lg[i] = s;
    }

    float m = lg[0];
    #pragma unroll
    for (int i = 1; i < 7; ++i) m = fmaxf(m, lg[i]);
    m = fmaxf(m, __shfl_xor(m, 1));
    m = fmaxf(m, __shfl_xor(m, 2));
    m = fmaxf(m, __shfl_xor(m, 4));
    float ssum = 0.f;
    #pragma unroll
    for (int i = 0; i < 7; ++i) {
        int j = t8 + i * 8;
        lg[i] = (j < 49) ? __expf(lg[i] - m) : 0.f;
        ssum += lg[i];
    }
    ssum += __shfl_xor(ssum, 1);
    ssum += __shfl_xor(ssum, 2);
    ssum += __shfl_xor(ssum, 4);
    float inv = 1.f / ssum;
    #pragma unroll
    for (int i = 0; i < 7; ++i) {
        int j = t8 + i * 8;
        if (j < 49) attn_s[q * 52 + j] = lg[i] * inv;   // wave-local relay
    }

    const int dd = t8 & 3;
    const int jp = t8 >> 2;
    float o[8] = {};
    #pragma unroll
    for (int i = 0; i < 25; ++i) {
        int j = 2 * i + jp;
        if (j < 49) {
            int p = (j * 37) >> 8;
            int qq = j - p * 7;
            int lp = base_lp + p * HALO_W + qq;
            int bb = (lp >> 2) & 1;
            float a = attn_s[q * 52 + j];
            uint4 vu = *(const uint4*)&KV_s[lp * 64 + (((2 * (dd ^ (lp & 3)) ^ bb) ^ 1) * 8)];
            o[0] += a * bflo(vu.x); o[1] += a * bfhi(vu.x);
            o[2] += a * bflo(vu.y); o[3] += a * bfhi(vu.y);
            o[4] += a * bflo(vu.z); o[5] += a * bfhi(vu.z);
            o[6] += a * bflo(vu.w); o[7] += a * bfhi(vu.w);
        }
    }
    #pragma unroll
    for (int e = 0; e < 8; ++e) o[e] += __shfl_xor(o[e], 4);

    if (t8 < 4) {
        union { ushort s[8]; uint4 u4; } w;
        #pragma unroll
        for (int e = 0; e < 8; ++e) w.s[e] = f2bf(o[e]);
        *(uint4*)(attn_out + qpix * 128 + hd * 32 + dd * 8) = w.u4;
    }
    __syncthreads();   // rep boundary: all KV_s/attn_s reads done
    }
}

// ---------------------------------------------------------------------------
// K3: proj GEMM (round-8 proven), amplified x REP_PROJ.
// ---------------------------------------------------------------------------
__global__ __launch_bounds__(256) void proj_gemm_kernel(
    const ushort* __restrict__ A,      // M x 128 bf16
    const ushort* __restrict__ Bt,     // [128][128] bf16, n-major
    const float* __restrict__ bias,    // 128
    float* __restrict__ C)             // M x 128 f32
{
    __shared__ ushort As[32 * 128];
    __shared__ ushort Bs[128 * 128];

    const int m0 = blockIdx.x * 32;
    const int tid = threadIdx.x;

    for (int rep = 0; rep < REP_PROJ; ++rep) {
    #pragma unroll
    for (int L = tid; L < 32 * 16; L += 256) {
        int r = L >> 4, c = L & 15;
        uint4 v = *(const uint4*)(A + (size_t)(m0 + r) * 128 + c * 8);
        *(uint4*)&As[r * 128 + (c ^ (r & 7)) * 8] = v;
    }
    #pragma unroll
    for (int L = tid; L < 128 * 16; L += 256) {
        int r = L >> 4, c = L & 15;
        uint4 v = *(const uint4*)(Bt + (size_t)r * 128 + c * 8);
        *(uint4*)&Bs[r * 128 + (c ^ (r & 7)) * 8] = v;
    }
    __syncthreads();

    const int wid = tid >> 6, lane = tid & 63;
    const int wr = wid >> 1, wc = wid & 1;
    const int mr = wr * 16, nr = wc * 64;
    const int l15 = lane & 15, l4 = lane >> 4;

    f32x4 acc[4] = {};
    #pragma unroll
    for (int ks = 0; ks < 4; ++ks) {
        int arow = mr + l15;
        short8 af = *(const short8*)&As[arow * 128 + ((ks * 4 + l4) ^ (arow & 7)) * 8];
        #pragma unroll
        for (int fn = 0; fn < 4; ++fn) {
            int brow = nr + fn * 16 + l15;
            short8 bf = *(const short8*)&Bs[brow * 128 + ((ks * 4 + l4) ^ (brow & 7)) * 8];
            acc[fn] = __builtin_amdgcn_mfma_f32_16x16x32_bf16(af, bf, acc[fn], 0, 0, 0);
        }
    }

    #pragma unroll
    for (int fn = 0; fn < 4; ++fn) {
        int col = nr + fn * 16 + l15;
        float bc = bias[col];
        #pragma unroll
        for (int reg = 0; reg < 4; ++reg) {
            int row = m0 + mr + l4 * 4 + reg;
            C[(size_t)row * 128 + col] = acc[fn][reg] + bc;
        }
    }
    __syncthreads();   // rep boundary: As/Bs reads done before next staging
    }
}

extern "C" void kernel_launch(void* const* d_in, const int* in_sizes, int n_in,
                              void* d_out, int out_size, void* d_ws, size_t ws_size,
                              hipStream_t stream)
{
    const float* x      = (const float*)d_in[0];
    const float* w_qkv  = (const float*)d_in[1];
    const float* b_qkv  = (const float*)d_in[2];
    const float* rpb    = (const float*)d_in[3];
    const float* w_proj = (const float*)d_in[4];
    const float* b_proj = (const float*)d_in[5];
    float* out = (float*)d_out;

    const int M = BB * HH * WW;                   // 8192
    ushort* qkv     = (ushort*)d_ws;              // M x 384 bf16
    ushort* attn_bf = qkv + (size_t)M * 384;      // M x 128 bf16
    ushort* Wt      = attn_bf + (size_t)M * 128;  // 512 x 128 bf16
    ushort* Wt_proj = Wt + (size_t)384 * 128;     // rows 384..511

    // MEASUREMENT ROUND 2: per-kernel amplification. Each amplified kernel's
    // dispatch dur exceeds the ~43us reset-fill dispatches -> appears in the
    // rocprof top-5 WITH counters. Per-kernel cost = amplified_dur / REP.
    cvt_w_kernel<<<8, 256, 0, stream>>>(w_qkv, w_proj, Wt);

    qkv_gemm_kernel<<<dim3(128, 2), 256, 0, stream>>>(x, Wt, b_qkv, qkv);

    natten_head_kernel<<<dim3(256, 4), 256, 0, stream>>>(qkv, rpb, attn_bf);

    proj_gemm_kernel<<<256, 256, 0, stream>>>(attn_bf, Wt_proj, b_proj, out);
}

// Round 12
// 32.726 us; speedup vs baseline: 4.9923x; 4.9923x over previous
//
#include <hip/hip_runtime.h>
#include <hip/hip_bf16.h>
#include <cstddef>

#define BB 2
#define HH 64
#define WW 64
#define SCALE 0.17677669529663687f   // 32^-0.5

// natten tile geometry: 4x8 queries per block
#define HALO_H 10
#define HALO_W 14
#define NPIX 140
#define NQ 32

typedef short short8 __attribute__((ext_vector_type(8)));
typedef float f32x4 __attribute__((ext_vector_type(4)));

__device__ inline ushort f2bf(float f) {
    union { __hip_bfloat16 b; ushort u; } cv;
    cv.b = __float2bfloat16(f);
    return cv.u;
}
__device__ inline float bflo(uint u) { union { uint i; float f; } c; c.i = u << 16; return c.f; }
__device__ inline float bfhi(uint u) { union { uint i; float f; } c; c.i = u & 0xffff0000u; return c.f; }

// ---------------------------------------------------------------------------
// K1: qkv = x @ w_qkv + b_qkv (q cols pre-scaled), bf16 out.
// B staged by coalesced gather-transpose from w_qkv (f32->bf16 in regs, no
// extra LDS/barriers). Blocks with by==0 also emit Wp_t (R5-proven side job).
// MFMA + LDS-transpose epilogue verbatim from the round-7..9 proven kernel.
// ---------------------------------------------------------------------------
__global__ __launch_bounds__(256) void qkv_gemm_fused_kernel(
    const float* __restrict__ x, const float* __restrict__ w_qkv,
    const float* __restrict__ b_qkv, const float* __restrict__ w_proj,
    ushort* __restrict__ qkv, ushort* __restrict__ Wp_t)
{
    __shared__ ushort As[64 * 128];    // 16KB
    __shared__ ushort Bs[192 * 128];   // 48KB  (total 64KB exactly)

    const int tid = threadIdx.x;
    const int m0 = blockIdx.x * 64;
    const int n0 = blockIdx.y * 192;

    // side job: Wp_t[n][k] = bf16(w_proj[k][n]), one n-row per (m,0) block
    if (blockIdx.y == 0 && tid < 128)
        Wp_t[(size_t)blockIdx.x * 128 + tid] =
            f2bf(w_proj[(size_t)tid * 128 + blockIdx.x]);

    // stage A: 64x128 f32 -> bf16 (proven)
    #pragma unroll
    for (int t = 0; t < 4; ++t) {
        int idx = tid + t * 256;
        int r = idx >> 4, c = idx & 15;
        const float* src = x + (size_t)(m0 + r) * 128 + c * 8;
        float4 v0 = *(const float4*)src;
        float4 v1 = *(const float4*)(src + 4);
        union { ushort s[8]; uint4 q; } u;
        u.s[0] = f2bf(v0.x); u.s[1] = f2bf(v0.y); u.s[2] = f2bf(v0.z); u.s[3] = f2bf(v0.w);
        u.s[4] = f2bf(v1.x); u.s[5] = f2bf(v1.y); u.s[6] = f2bf(v1.z); u.s[7] = f2bf(v1.w);
        *(uint4*)&As[r * 128 + (c ^ (r & 7)) * 8] = u.q;
    }
    // stage B: gather-transpose w_qkv[k][n0+n] -> Bs[n][k] bf16.
    // thread handles (n = idx % 192, kc = idx / 192): 8 coalesced f32 reads
    // (lanes walk n -> 256B lines, w_qkv is L2-resident), one uint4 LDS write.
    #pragma unroll
    for (int t = 0; t < 12; ++t) {
        int idx = tid + t * 256;           // 0..3071
        int kc = idx / 192, n = idx - kc * 192;
        union { ushort s[8]; uint4 q; } u;
        #pragma unroll
        for (int e = 0; e < 8; ++e)
            u.s[e] = f2bf(w_qkv[(size_t)(kc * 8 + e) * 384 + n0 + n]);
        *(uint4*)&Bs[n * 128 + ((kc ^ (n & 7)) * 8)] = u.q;
    }
    __syncthreads();

    const int wid = tid >> 6, lane = tid & 63;
    const int l15 = lane & 15, l4 = lane >> 4;
    const int mr = (wid >> 1) * 32, nr = (wid & 1) * 96;

    f32x4 acc[2][6] = {};
    #pragma unroll
    for (int ks = 0; ks < 4; ++ks) {
        short8 af[2], bf[6];
        #pragma unroll
        for (int fm = 0; fm < 2; ++fm) {
            int row = mr + fm * 16 + l15;
            af[fm] = *(const short8*)&As[row * 128 + ((ks * 4 + l4) ^ (row & 7)) * 8];
        }
        #pragma unroll
        for (int fn = 0; fn < 6; ++fn) {
            int row = nr + fn * 16 + l15;
            bf[fn] = *(const short8*)&Bs[row * 128 + ((ks * 4 + l4) ^ (row & 7)) * 8];
        }
        #pragma unroll
        for (int fm = 0; fm < 2; ++fm)
            #pragma unroll
            for (int fn = 0; fn < 6; ++fn)
                acc[fm][fn] = __builtin_amdgcn_mfma_f32_16x16x32_bf16(
                    af[fm], bf[fn], acc[fm][fn], 0, 0, 0);
    }

    __syncthreads();
    ushort* C_s = Bs;                     // 64 x 200 overlay (proven)
    #pragma unroll
    for (int fn = 0; fn < 6; ++fn) {
        int colb = nr + fn * 16;
        int col = colb + l15;
        float bc = b_qkv[n0 + col];
        float sc = (n0 + colb < 128) ? SCALE : 1.0f;
        #pragma unroll
        for (int fm = 0; fm < 2; ++fm)
            #pragma unroll
            for (int reg = 0; reg < 4; ++reg) {
                int row = mr + fm * 16 + l4 * 4 + reg;
                C_s[row * 200 + col] = f2bf((acc[fm][fn][reg] + bc) * sc);
            }
    }
    __syncthreads();
    #pragma unroll
    for (int t = 0; t < 6; ++t) {
        int idx = tid + t * 256;
        int row = idx / 24, c = idx - row * 24;
        uint4 v = *(const uint4*)&C_s[row * 200 + c * 8];
        *(uint4*)&qkv[(size_t)(m0 + row) * 384 + n0 + c * 8] = v;
    }
}

// ---------------------------------------------------------------------------
// K2: fused neighborhood attention (4-head loop, round-9 proven body per
// head) + output projection (round-5 proven proj). Grid 256, ~35KB LDS.
// KV re-staged per head (R9 conflict-free interleaved layout); PV result
// accumulated in AO_s bf16 (R5 swizzle); proj B-frags from L2-hot Wp_t.
// ---------------------------------------------------------------------------
__global__ __launch_bounds__(256) void natten_proj_kernel(
    const ushort* __restrict__ qkv,     // (B*H*W) x 384 bf16, q pre-scaled
    const float* __restrict__ rpb,      // 4 x 13 x 13
    const ushort* __restrict__ Wp_t,    // 128 x 128 bf16, [n][k]
    const float* __restrict__ b_proj,   // 128
    float* __restrict__ out)            // (B*H*W) x 128 f32
{
    __shared__ ushort KV_s[NPIX * 64];  // 17.5KB
    __shared__ ushort AO_s[NQ * 128];   // 8KB
    __shared__ float attn_s[NQ * 52];   // 6.5KB
    __shared__ float rpb_s[676];        // 2.7KB

    const int tid = threadIdx.x;
    // XCD-aware swizzle (256 % 8 == 0 -> bijective, R5-proven decode)
    const int bx = ((blockIdx.x & 7) << 5) | (blockIdx.x >> 3);
    const int b  = bx >> 7;
    const int th = (bx >> 3) & 15;
    const int tw = bx & 7;
    const int h0 = th * 4, w0 = tw * 8;
    const int ho = max(0, h0 - 3), wo = max(0, w0 - 3);

    #pragma unroll
    for (int t = 0; t < 3; ++t) {
        int idx = tid + t * 256;
        if (idx < 676) rpb_s[idx] = rpb[idx];
    }

    // per-thread query mapping: 32 queries x 8 lanes (proven)
    const int q = tid >> 3, t8 = tid & 7;
    const int qh = h0 + (q >> 3), qw = w0 + (q & 7);
    const int hs = min(max(qh - 3, 0), HH - 7);
    const int ws = min(max(qw - 3, 0), WW - 7);
    const int base_lp = (hs - ho) * HALO_W + (ws - wo);
    const int bh0 = hs - qh + 6, bw0 = ws - qw + 6;
    const size_t qpix = (size_t)((b << 12) + (qh << 6) + qw);

    for (int hd = 0; hd < 4; ++hd) {
        // ---- stage K/V for this head (R9 conflict-free layout) ----
        #pragma unroll
        for (int t = 0; t < 5; ++t) {
            int idx = tid + t * 256;
            if (idx < NPIX * 8) {
                int pix = idx >> 3, s = idx & 7;
                int r = pix / HALO_W, c = pix - r * HALO_W;
                int gh = min(ho + r, HH - 1), gw = min(wo + c, WW - 1);
                const ushort* gp = qkv + (size_t)((b << 12) + (gh << 6) + gw) * 384
                                   + 128 + (s >> 2) * 128 + hd * 32 + (s & 3) * 8;
                uint4 v = *(const uint4*)gp;
                int bb = (pix >> 2) & 1;
                int slot = (2 * ((s & 3) ^ (pix & 3)) ^ bb) ^ (s >> 2);
                *(uint4*)&KV_s[pix * 64 + slot * 8] = v;
            }
        }

        float qf[32];
        #pragma unroll
        for (int d4 = 0; d4 < 4; ++d4) {
            uint4 qu = *(const uint4*)(qkv + qpix * 384 + hd * 32 + d4 * 8);
            qf[d4*8+0] = bflo(qu.x); qf[d4*8+1] = bfhi(qu.x);
            qf[d4*8+2] = bflo(qu.y); qf[d4*8+3] = bfhi(qu.y);
            qf[d4*8+4] = bflo(qu.z); qf[d4*8+5] = bfhi(qu.z);
            qf[d4*8+6] = bflo(qu.w); qf[d4*8+7] = bfhi(qu.w);
        }
        __syncthreads();

        // ---- QK + bias (R9 proven) ----
        float lg[7];
        #pragma unroll
        for (int i = 0; i < 7; ++i) {
            int j = t8 + i * 8;
            float s = -1e30f;
            if (j < 49) {
                int p = (j * 37) >> 8;        // exact j/7 for j<=48
                int qq = j - p * 7;
                int lp = base_lp + p * HALO_W + qq;
                int bb = (lp >> 2) & 1;
                float a = 0.f;
                #pragma unroll
                for (int d4 = 0; d4 < 4; ++d4) {
                    uint4 ku = *(const uint4*)&KV_s[lp * 64 + ((2 * (d4 ^ (lp & 3)) ^ bb) * 8)];
                    a += bflo(ku.x)*qf[d4*8+0] + bfhi(ku.x)*qf[d4*8+1]
                       + bflo(ku.y)*qf[d4*8+2] + bfhi(ku.y)*qf[d4*8+3]
                       + bflo(ku.z)*qf[d4*8+4] + bfhi(ku.z)*qf[d4*8+5]
                       + bflo(ku.w)*qf[d4*8+6] + bfhi(ku.w)*qf[d4*8+7];
                }
                s = a + rpb_s[hd * 169 + (bh0 + p) * 13 + (bw0 + qq)];
            }
            lg[i] = s;
        }

        // ---- softmax across the query's 8 lanes (proven) ----
        float m = lg[0];
        #pragma unroll
        for (int i = 1; i < 7; ++i) m = fmaxf(m, lg[i]);
        m = fmaxf(m, __shfl_xor(m, 1));
        m = fmaxf(m, __shfl_xor(m, 2));
        m = fmaxf(m, __shfl_xor(m, 4));
        float ssum = 0.f;
        #pragma unroll
        for (int i = 0; i < 7; ++i) {
            int j = t8 + i * 8;
            lg[i] = (j < 49) ? __expf(lg[i] - m) : 0.f;
            ssum += lg[i];
        }
        ssum += __shfl_xor(ssum, 1);
        ssum += __shfl_xor(ssum, 2);
        ssum += __shfl_xor(ssum, 4);
        float inv = 1.f / ssum;
        #pragma unroll
        for (int i = 0; i < 7; ++i) {
            int j = t8 + i * 8;
            if (j < 49) attn_s[q * 52 + j] = lg[i] * inv;   // wave-local
        }

        // ---- PV (R9 proven): lane (dd = t8&3, jp = t8>>2) ----
        const int dd = t8 & 3;
        const int jp = t8 >> 2;
        float o[8] = {};
        #pragma unroll
        for (int i = 0; i < 25; ++i) {
            int j = 2 * i + jp;
            if (j < 49) {
                int p = (j * 37) >> 8;
                int qq = j - p * 7;
                int lp = base_lp + p * HALO_W + qq;
                int bb = (lp >> 2) & 1;
                float a = attn_s[q * 52 + j];
                uint4 vu = *(const uint4*)&KV_s[lp * 64 + (((2 * (dd ^ (lp & 3)) ^ bb) ^ 1) * 8)];
                o[0] += a * bflo(vu.x); o[1] += a * bfhi(vu.x);
                o[2] += a * bflo(vu.y); o[3] += a * bfhi(vu.y);
                o[4] += a * bflo(vu.z); o[5] += a * bfhi(vu.z);
                o[6] += a * bflo(vu.w); o[7] += a * bfhi(vu.w);
            }
        }
        #pragma unroll
        for (int e = 0; e < 8; ++e) o[e] += __shfl_xor(o[e], 4);

        if (t8 < 4) {
            union { ushort s[8]; uint4 u4; } w;
            #pragma unroll
            for (int e = 0; e < 8; ++e) w.s[e] = f2bf(o[e]);
            // AO_s chunk index c = hd*4+dd (0..15), R5-proven (c ^ (q&7)) swizzle
            *(uint4*)&AO_s[q * 128 + (((hd * 4 + dd) ^ (q & 7)) * 8)] = w.u4;
        }
        __syncthreads();   // KV_s/attn_s reuse boundary; also guards AO_s->proj
    }

    // ---- proj: out(32x128) = AO @ Wp^T + b_proj (R5 proven) ----
    const int wid = tid >> 6, lane = tid & 63;
    const int l15 = lane & 15, l4 = lane >> 4;
    const int wr = wid >> 1, wc = wid & 1;

    f32x4 pacc[4] = {};
    #pragma unroll
    for (int ks = 0; ks < 4; ++ks) {
        int arow = wr * 16 + l15;
        short8 af = *(const short8*)&AO_s[arow * 128 + ((ks * 4 + l4) ^ (arow & 7)) * 8];
        #pragma unroll
        for (int fn = 0; fn < 4; ++fn) {
            int brow = wc * 64 + fn * 16 + l15;
            short8 bf = *(const short8*)(Wp_t + (size_t)brow * 128 + (ks * 4 + l4) * 8);
            pacc[fn] = __builtin_amdgcn_mfma_f32_16x16x32_bf16(af, bf, pacc[fn], 0, 0, 0);
        }
    }
    #pragma unroll
    for (int fn = 0; fn < 4; ++fn) {
        int col = wc * 64 + fn * 16 + l15;
        float bc = b_proj[col];
        #pragma unroll
        for (int reg = 0; reg < 4; ++reg) {
            int q2 = wr * 16 + l4 * 4 + reg;
            int oh = h0 + (q2 >> 3), ow = w0 + (q2 & 7);
            out[(size_t)((b << 12) + (oh << 6) + ow) * 128 + col] = pacc[fn][reg] + bc;
        }
    }
}

extern "C" void kernel_launch(void* const* d_in, const int* in_sizes, int n_in,
                              void* d_out, int out_size, void* d_ws, size_t ws_size,
                              hipStream_t stream)
{
    const float* x      = (const float*)d_in[0];
    const float* w_qkv  = (const float*)d_in[1];
    const float* b_qkv  = (const float*)d_in[2];
    const float* rpb    = (const float*)d_in[3];
    const float* w_proj = (const float*)d_in[4];
    const float* b_proj = (const float*)d_in[5];
    float* out = (float*)d_out;

    const int M = BB * HH * WW;                   // 8192
    ushort* qkv  = (ushort*)d_ws;                 // M x 384 bf16
    ushort* Wp_t = qkv + (size_t)M * 384;         // 128 x 128 bf16

    qkv_gemm_fused_kernel<<<dim3(128, 2), 256, 0, stream>>>(
        x, w_qkv, b_qkv, w_proj, qkv, Wp_t);

    natten_proj_kernel<<<256, 256, 0, stream>>>(
        qkv, rpb, Wp_t, b_proj, out);
}

// Round 13
// 30.333 us; speedup vs baseline: 5.3861x; 1.0789x over previous
//
#include <hip/hip_runtime.h>
#include <hip/hip_bf16.h>
#include <cstddef>

#define BB 2
#define HH 64
#define WW 64
#define SCALE 0.17677669529663687f   // 32^-0.5

// natten tile geometry: 4x8 queries per block
#define HALO_H 10
#define HALO_W 14
#define NPIX 140
#define NQ 32

typedef short short8 __attribute__((ext_vector_type(8)));
typedef float f32x4 __attribute__((ext_vector_type(4)));

#if defined(__has_builtin)
#if __has_builtin(__builtin_amdgcn_fdot2_f32_bf16)
#define HAS_BFDOT2 1
#endif
#endif
#ifndef HAS_BFDOT2
#define HAS_BFDOT2 0
#endif

#if HAS_BFDOT2
typedef __bf16 v2bf __attribute__((ext_vector_type(2)));
__device__ inline float bfdot2(uint a, uint b, float c) {
    union { uint u; v2bf v; } ua, ub;
    ua.u = a; ub.u = b;
    return __builtin_amdgcn_fdot2_f32_bf16(ua.v, ub.v, c, false);
}
#endif

__device__ inline ushort f2bf(float f) {
    union { __hip_bfloat16 b; ushort u; } cv;
    cv.b = __float2bfloat16(f);
    return cv.u;
}
__device__ inline float bflo(uint u) { union { uint i; float f; } c; c.i = u << 16; return c.f; }
__device__ inline float bfhi(uint u) { union { uint i; float f; } c; c.i = u & 0xffff0000u; return c.f; }

// ---------------------------------------------------------------------------
// K1: qkv = x @ w_qkv + b_qkv (q cols pre-scaled), bf16 out.
// BN 192->96, LDS 40KB, grid (128,4)=512 -> 2 blocks/CU (latency hiding for
// the scalar gather-transpose B staging). Structure otherwise R12-proven.
// Blocks with by==0 also emit Wp_t (proven side job).
// ---------------------------------------------------------------------------
__global__ __launch_bounds__(256) void qkv_gemm_fused_kernel(
    const float* __restrict__ x, const float* __restrict__ w_qkv,
    const float* __restrict__ b_qkv, const float* __restrict__ w_proj,
    ushort* __restrict__ qkv, ushort* __restrict__ Wp_t)
{
    __shared__ ushort S[64 * 128 + 96 * 128];   // As | Bs  (40KB)
    ushort* As = S;
    ushort* Bs = S + 64 * 128;

    const int tid = threadIdx.x;
    const int m0 = blockIdx.x * 64;
    const int n0 = blockIdx.y * 96;

    // side job: Wp_t[n][k] = bf16(w_proj[k][n]), one n-row per (m,0) block
    if (blockIdx.y == 0 && tid < 128)
        Wp_t[(size_t)blockIdx.x * 128 + tid] =
            f2bf(w_proj[(size_t)tid * 128 + blockIdx.x]);

    // stage A: 64x128 f32 -> bf16 (proven)
    #pragma unroll
    for (int t = 0; t < 4; ++t) {
        int idx = tid + t * 256;
        int r = idx >> 4, c = idx & 15;
        const float* src = x + (size_t)(m0 + r) * 128 + c * 8;
        float4 v0 = *(const float4*)src;
        float4 v1 = *(const float4*)(src + 4);
        union { ushort s[8]; uint4 q; } u;
        u.s[0] = f2bf(v0.x); u.s[1] = f2bf(v0.y); u.s[2] = f2bf(v0.z); u.s[3] = f2bf(v0.w);
        u.s[4] = f2bf(v1.x); u.s[5] = f2bf(v1.y); u.s[6] = f2bf(v1.z); u.s[7] = f2bf(v1.w);
        *(uint4*)&As[r * 128 + (c ^ (r & 7)) * 8] = u.q;
    }
    // stage B: gather-transpose w_qkv[k][n0+n] -> Bs[n][k] bf16 (96 cols)
    #pragma unroll
    for (int t = 0; t < 6; ++t) {
        int idx = tid + t * 256;           // 0..1535
        int kc = idx / 96, n = idx - kc * 96;
        union { ushort s[8]; uint4 q; } u;
        #pragma unroll
        for (int e = 0; e < 8; ++e)
            u.s[e] = f2bf(w_qkv[(size_t)(kc * 8 + e) * 384 + n0 + n]);
        *(uint4*)&Bs[n * 128 + ((kc ^ (n & 7)) * 8)] = u.q;
    }
    __syncthreads();

    const int wid = tid >> 6, lane = tid & 63;
    const int l15 = lane & 15, l4 = lane >> 4;
    const int mr = (wid >> 1) * 32, nr = (wid & 1) * 48;

    f32x4 acc[2][3] = {};
    #pragma unroll
    for (int ks = 0; ks < 4; ++ks) {
        short8 af[2], bf[3];
        #pragma unroll
        for (int fm = 0; fm < 2; ++fm) {
            int row = mr + fm * 16 + l15;
            af[fm] = *(const short8*)&As[row * 128 + ((ks * 4 + l4) ^ (row & 7)) * 8];
        }
        #pragma unroll
        for (int fn = 0; fn < 3; ++fn) {
            int row = nr + fn * 16 + l15;
            bf[fn] = *(const short8*)&Bs[row * 128 + ((ks * 4 + l4) ^ (row & 7)) * 8];
        }
        #pragma unroll
        for (int fm = 0; fm < 2; ++fm)
            #pragma unroll
            for (int fn = 0; fn < 3; ++fn)
                acc[fm][fn] = __builtin_amdgcn_mfma_f32_16x16x32_bf16(
                    af[fm], bf[fn], acc[fm][fn], 0, 0, 0);
    }

    __syncthreads();
    ushort* C_s = S;                      // 64 x 200 overlay (25.6KB <= 40KB)
    #pragma unroll
    for (int fn = 0; fn < 3; ++fn) {
        int colb = nr + fn * 16;
        int col = colb + l15;
        float bc = b_qkv[n0 + col];
        float sc = (n0 + colb < 128) ? SCALE : 1.0f;
        #pragma unroll
        for (int fm = 0; fm < 2; ++fm)
            #pragma unroll
            for (int reg = 0; reg < 4; ++reg) {
                int row = mr + fm * 16 + l4 * 4 + reg;
                C_s[row * 200 + col] = f2bf((acc[fm][fn][reg] + bc) * sc);
            }
    }
    __syncthreads();
    #pragma unroll
    for (int t = 0; t < 3; ++t) {
        int idx = tid + t * 256;           // 0..767 over 64 rows x 12 chunks
        int row = idx / 12, c = idx - row * 12;
        uint4 v = *(const uint4*)&C_s[row * 200 + c * 8];
        *(uint4*)&qkv[(size_t)(m0 + row) * 384 + n0 + c * 8] = v;
    }
}

// ---------------------------------------------------------------------------
// K2: fused neighborhood attention (4-head loop) + output projection
// (R12-proven). QK inner product upgraded to v_dot2_f32_bf16 when available
// (halves QK VALU and kills q-extraction); PV/softmax/proj verbatim.
// ---------------------------------------------------------------------------
__global__ __launch_bounds__(256) void natten_proj_kernel(
    const ushort* __restrict__ qkv,     // (B*H*W) x 384 bf16, q pre-scaled
    const float* __restrict__ rpb,      // 4 x 13 x 13
    const ushort* __restrict__ Wp_t,    // 128 x 128 bf16, [n][k]
    const float* __restrict__ b_proj,   // 128
    float* __restrict__ out)            // (B*H*W) x 128 f32
{
    __shared__ ushort KV_s[NPIX * 64];  // 17.5KB
    __shared__ ushort AO_s[NQ * 128];   // 8KB
    __shared__ float attn_s[NQ * 52];   // 6.5KB
    __shared__ float rpb_s[676];        // 2.7KB

    const int tid = threadIdx.x;
    // XCD-aware swizzle (256 % 8 == 0 -> bijective, proven decode)
    const int bx = ((blockIdx.x & 7) << 5) | (blockIdx.x >> 3);
    const int b  = bx >> 7;
    const int th = (bx >> 3) & 15;
    const int tw = bx & 7;
    const int h0 = th * 4, w0 = tw * 8;
    const int ho = max(0, h0 - 3), wo = max(0, w0 - 3);

    #pragma unroll
    for (int t = 0; t < 3; ++t) {
        int idx = tid + t * 256;
        if (idx < 676) rpb_s[idx] = rpb[idx];
    }

    // per-thread query mapping: 32 queries x 8 lanes (proven)
    const int q = tid >> 3, t8 = tid & 7;
    const int qh = h0 + (q >> 3), qw = w0 + (q & 7);
    const int hs = min(max(qh - 3, 0), HH - 7);
    const int ws = min(max(qw - 3, 0), WW - 7);
    const int base_lp = (hs - ho) * HALO_W + (ws - wo);
    const int bh0 = hs - qh + 6, bw0 = ws - qw + 6;
    const size_t qpix = (size_t)((b << 12) + (qh << 6) + qw);

    for (int hd = 0; hd < 4; ++hd) {
        // ---- stage K/V for this head (R9-proven conflict-free layout) ----
        #pragma unroll
        for (int t = 0; t < 5; ++t) {
            int idx = tid + t * 256;
            if (idx < NPIX * 8) {
                int pix = idx >> 3, s = idx & 7;
                int r = pix / HALO_W, c = pix - r * HALO_W;
                int gh = min(ho + r, HH - 1), gw = min(wo + c, WW - 1);
                const ushort* gp = qkv + (size_t)((b << 12) + (gh << 6) + gw) * 384
                                   + 128 + (s >> 2) * 128 + hd * 32 + (s & 3) * 8;
                uint4 v = *(const uint4*)gp;
                int bb = (pix >> 2) & 1;
                int slot = (2 * ((s & 3) ^ (pix & 3)) ^ bb) ^ (s >> 2);
                *(uint4*)&KV_s[pix * 64 + slot * 8] = v;
            }
        }

        // Q for this head
#if HAS_BFDOT2
        uint4 qb[4];
        #pragma unroll
        for (int d4 = 0; d4 < 4; ++d4)
            qb[d4] = *(const uint4*)(qkv + qpix * 384 + hd * 32 + d4 * 8);
#else
        float qf[32];
        #pragma unroll
        for (int d4 = 0; d4 < 4; ++d4) {
            uint4 qu = *(const uint4*)(qkv + qpix * 384 + hd * 32 + d4 * 8);
            qf[d4*8+0] = bflo(qu.x); qf[d4*8+1] = bfhi(qu.x);
            qf[d4*8+2] = bflo(qu.y); qf[d4*8+3] = bfhi(qu.y);
            qf[d4*8+4] = bflo(qu.z); qf[d4*8+5] = bfhi(qu.z);
            qf[d4*8+6] = bflo(qu.w); qf[d4*8+7] = bfhi(qu.w);
        }
#endif
        __syncthreads();

        // ---- QK + bias: lane t8 handles j = t8, t8+8, ... ----
        float lg[7];
        #pragma unroll
        for (int i = 0; i < 7; ++i) {
            int j = t8 + i * 8;
            float s = -1e30f;
            if (j < 49) {
                int p = (j * 37) >> 8;        // exact j/7 for j<=48
                int qq = j - p * 7;
                int lp = base_lp + p * HALO_W + qq;
                int bb = (lp >> 2) & 1;
                float a = 0.f;
                #pragma unroll
                for (int d4 = 0; d4 < 4; ++d4) {
                    uint4 ku = *(const uint4*)&KV_s[lp * 64 + ((2 * (d4 ^ (lp & 3)) ^ bb) * 8)];
#if HAS_BFDOT2
                    a = bfdot2(ku.x, qb[d4].x, a);
                    a = bfdot2(ku.y, qb[d4].y, a);
                    a = bfdot2(ku.z, qb[d4].z, a);
                    a = bfdot2(ku.w, qb[d4].w, a);
#else
                    a += bflo(ku.x)*qf[d4*8+0] + bfhi(ku.x)*qf[d4*8+1]
                       + bflo(ku.y)*qf[d4*8+2] + bfhi(ku.y)*qf[d4*8+3]
                       + bflo(ku.z)*qf[d4*8+4] + bfhi(ku.z)*qf[d4*8+5]
                       + bflo(ku.w)*qf[d4*8+6] + bfhi(ku.w)*qf[d4*8+7];
#endif
                }
                s = a + rpb_s[hd * 169 + (bh0 + p) * 13 + (bw0 + qq)];
            }
            lg[i] = s;
        }

        // ---- softmax across the query's 8 lanes (proven) ----
        float m = lg[0];
        #pragma unroll
        for (int i = 1; i < 7; ++i) m = fmaxf(m, lg[i]);
        m = fmaxf(m, __shfl_xor(m, 1));
        m = fmaxf(m, __shfl_xor(m, 2));
        m = fmaxf(m, __shfl_xor(m, 4));
        float ssum = 0.f;
        #pragma unroll
        for (int i = 0; i < 7; ++i) {
            int j = t8 + i * 8;
            lg[i] = (j < 49) ? __expf(lg[i] - m) : 0.f;
            ssum += lg[i];
        }
        ssum += __shfl_xor(ssum, 1);
        ssum += __shfl_xor(ssum, 2);
        ssum += __shfl_xor(ssum, 4);
        float inv = 1.f / ssum;
        #pragma unroll
        for (int i = 0; i < 7; ++i) {
            int j = t8 + i * 8;
            if (j < 49) attn_s[q * 52 + j] = lg[i] * inv;   // wave-local
        }

        // ---- PV (proven): lane (dd = t8&3, jp = t8>>2) ----
        const int dd = t8 & 3;
        const int jp = t8 >> 2;
        float o[8] = {};
        #pragma unroll
        for (int i = 0; i < 25; ++i) {
            int j = 2 * i + jp;
            if (j < 49) {
                int p = (j * 37) >> 8;
                int qq = j - p * 7;
                int lp = base_lp + p * HALO_W + qq;
                int bb = (lp >> 2) & 1;
                float a = attn_s[q * 52 + j];
                uint4 vu = *(const uint4*)&KV_s[lp * 64 + (((2 * (dd ^ (lp & 3)) ^ bb) ^ 1) * 8)];
                o[0] += a * bflo(vu.x); o[1] += a * bfhi(vu.x);
                o[2] += a * bflo(vu.y); o[3] += a * bfhi(vu.y);
                o[4] += a * bflo(vu.z); o[5] += a * bfhi(vu.z);
                o[6] += a * bflo(vu.w); o[7] += a * bfhi(vu.w);
            }
        }
        #pragma unroll
        for (int e = 0; e < 8; ++e) o[e] += __shfl_xor(o[e], 4);

        if (t8 < 4) {
            union { ushort s[8]; uint4 u4; } w;
            #pragma unroll
            for (int e = 0; e < 8; ++e) w.s[e] = f2bf(o[e]);
            *(uint4*)&AO_s[q * 128 + (((hd * 4 + dd) ^ (q & 7)) * 8)] = w.u4;
        }
        __syncthreads();   // KV_s/attn_s reuse boundary; also guards AO_s->proj
    }

    // ---- proj: out(32x128) = AO @ Wp^T + b_proj (proven) ----
    const int wid = tid >> 6, lane = tid & 63;
    const int l15 = lane & 15, l4 = lane >> 4;
    const int wr = wid >> 1, wc = wid & 1;

    f32x4 pacc[4] = {};
    #pragma unroll
    for (int ks = 0; ks < 4; ++ks) {
        int arow = wr * 16 + l15;
        short8 af = *(const short8*)&AO_s[arow * 128 + ((ks * 4 + l4) ^ (arow & 7)) * 8];
        #pragma unroll
        for (int fn = 0; fn < 4; ++fn) {
            int brow = wc * 64 + fn * 16 + l15;
            short8 bf = *(const short8*)(Wp_t + (size_t)brow * 128 + (ks * 4 + l4) * 8);
            pacc[fn] = __builtin_amdgcn_mfma_f32_16x16x32_bf16(af, bf, pacc[fn], 0, 0, 0);
        }
    }
    #pragma unroll
    for (int fn = 0; fn < 4; ++fn) {
        int col = wc * 64 + fn * 16 + l15;
        float bc = b_proj[col];
        #pragma unroll
        for (int reg = 0; reg < 4; ++reg) {
            int q2 = wr * 16 + l4 * 4 + reg;
            int oh = h0 + (q2 >> 3), ow = w0 + (q2 & 7);
            out[(size_t)((b << 12) + (oh << 6) + ow) * 128 + col] = pacc[fn][reg] + bc;
        }
    }
}

extern "C" void kernel_launch(void* const* d_in, const int* in_sizes, int n_in,
                              void* d_out, int out_size, void* d_ws, size_t ws_size,
                              hipStream_t stream)
{
    const float* x      = (const float*)d_in[0];
    const float* w_qkv  = (const float*)d_in[1];
    const float* b_qkv  = (const float*)d_in[2];
    const float* rpb    = (const float*)d_in[3];
    const float* w_proj = (const float*)d_in[4];
    const float* b_proj = (const float*)d_in[5];
    float* out = (float*)d_out;

    const int M = BB * HH * WW;                   // 8192
    ushort* qkv  = (ushort*)d_ws;                 // M x 384 bf16
    ushort* Wp_t = qkv + (size_t)M * 384;         // 128 x 128 bf16

    qkv_gemm_fused_kernel<<<dim3(128, 4), 256, 0, stream>>>(
        x, w_qkv, b_qkv, w_proj, qkv, Wp_t);

    natten_proj_kernel<<<256, 256, 0, stream>>>(
        qkv, rpb, Wp_t, b_proj, out);
}